// Round 6
// baseline (52.353 us; speedup 1.0000x reference)
//
#include <hip/hip_runtime.h>

#define G_ 1024
#define DIN_ 3072
#define B_ 8192
#define TB 4          // rows staged per block (48 KiB LDS)
#define TPB 512
#define GPT 2         // consecutive groups per thread

// ---------------------------------------------------------------------------
// Fused single kernel.
// out[b,g,m] = K + cx0*x0 + cx1*x1 + cx2*x2 + cq01*x0x1 + cq02*x0x2 + cq12*x1x2
// where x_i = x[b, conn[g,i]]; the 7 coeffs per (g,m) fold the soft-gate,
// the 6 Fredkin permutations, and the softmax weights.
//
// Schedule per block:
//   0) issue conn/sel/wg vector loads (phase-2 operands)
//   1) issue 6x global_load_lds (TB rows -> 48 KiB LDS, linear dest)
//   2) recompute 2 groups' coefficients in registers
//   3) __syncthreads
//   4) 4 rows x { 6 LDS gathers, 42 FMA, 24 B contiguous store }
// 512 thr, VGPR ~44-64, 48 KiB LDS, __launch_bounds__(512,6) -> 3 blocks/CU
// (24 waves/CU): while one block drains its stage, two others compute.
// ---------------------------------------------------------------------------
__global__ __launch_bounds__(TPB, 6) void fredkin_fused_kernel(
    const float* __restrict__ x, const int* __restrict__ conn,
    const float* __restrict__ sel, const float* __restrict__ wg,
    float* __restrict__ out)
{
    __shared__ float xs[TB * DIN_];   // 48 KiB
    const int t = threadIdx.x;
    const int row0 = blockIdx.x * TB;

    // ---- phase 0: param loads first (needed soonest, by phase 2) ----
    const int g0 = t * GPT;
    int   cc[GPT][3];
    float ss[GPT][3];
    float ww[GPT][6];
#pragma unroll
    for (int gi = 0; gi < GPT; ++gi) {
#pragma unroll
        for (int i = 0; i < 3; ++i) cc[gi][i] = conn[(g0 + gi) * 3 + i];
#pragma unroll
        for (int i = 0; i < 3; ++i) ss[gi][i] = sel[(g0 + gi) * 3 + i];
#pragma unroll
        for (int p = 0; p < 6; ++p) ww[gi][p] = wg[(g0 + gi) * 6 + p];
    }

    // ---- phase 1: issue direct-to-LDS stage (6 x 16 B per thread) ----
    const float4* xv = (const float4*)(x + (size_t)row0 * DIN_);
    float4* sv = (float4*)xs;
#pragma unroll
    for (int i = 0; i < (TB * DIN_ / 4) / TPB; ++i)   // 6 iters
        __builtin_amdgcn_global_load_lds(
            (const __attribute__((address_space(1))) void*)(xv + t + i * TPB),
            (__attribute__((address_space(3))) void*)(sv + t + i * TPB),
            16, 0, 0);

    // ---- phase 2: coefficient recompute for GPT consecutive groups ----
    float CF[GPT][3][7];   // per m: K, cx0, cx1, cx2, cq01, cq02, cq12
#pragma unroll
    for (int gi = 0; gi < GPT; ++gi) {
        float u[3], v[3];
#pragma unroll
        for (int i = 0; i < 3; ++i) {
            float s = ss[gi][i];
            float C = s / (1.0f + fabsf(s));
            float a = fabsf(C);
            u[i] = 1.0f - a;
            v[i] = 0.5f * (C + a);
        }

        // softmax over 6 permutation weights
        float w[6];
        float mx = -1e30f;
#pragma unroll
        for (int p = 0; p < 6; ++p) mx = fmaxf(mx, ww[gi][p]);
        float sum = 0.0f;
#pragma unroll
        for (int p = 0; p < 6; ++p) { w[p] = __expf(ww[gi][p] - mx); sum += w[p]; }
        float inv = 1.0f / sum;
#pragma unroll
        for (int p = 0; p < 6; ++p) w[p] *= inv;

        // itertools.permutations(range(3)); signals:
        // m0 = a ; m1 = c + ab - ac ; m2 = b - ab + ac  (a,b,c = permuted gated)
        const int P[6][3] = {{0,1,2},{0,2,1},{1,0,2},{1,2,0},{2,0,1},{2,1,0}};
        float L[3][3] = {{0.f,0.f,0.f},{0.f,0.f,0.f},{0.f,0.f,0.f}};
        float Q[3][3] = {{0.f,0.f,0.f},{0.f,0.f,0.f},{0.f,0.f,0.f}};
#pragma unroll
        for (int p = 0; p < 6; ++p) {
            int i0 = P[p][0], i1 = P[p][1], i2 = P[p][2];
            float wp = w[p];
            int p01 = i0 + i1 - 1;   // pair idx (i,j)->i+j-1, i<j
            int p02 = i0 + i2 - 1;
            L[0][i0] += wp;
            L[1][i2] += wp; Q[1][p01] += wp; Q[1][p02] -= wp;
            L[2][i1] += wp; Q[2][p01] -= wp; Q[2][p02] += wp;
        }

        // substitute gated_i = u_i*x_i + v_i -> x-space coefficients
#pragma unroll
        for (int m = 0; m < 3; ++m) {
            CF[gi][m][0] = L[m][0]*v[0] + L[m][1]*v[1] + L[m][2]*v[2]
                         + Q[m][0]*v[0]*v[1] + Q[m][1]*v[0]*v[2] + Q[m][2]*v[1]*v[2];
            CF[gi][m][1] = u[0]*(L[m][0] + Q[m][0]*v[1] + Q[m][1]*v[2]);
            CF[gi][m][2] = u[1]*(L[m][1] + Q[m][0]*v[0] + Q[m][2]*v[2]);
            CF[gi][m][3] = u[2]*(L[m][2] + Q[m][1]*v[0] + Q[m][2]*v[1]);
            CF[gi][m][4] = Q[m][0]*u[0]*u[1];
            CF[gi][m][5] = Q[m][1]*u[0]*u[2];
            CF[gi][m][6] = Q[m][2]*u[1]*u[2];
        }
    }

    // ---- phase 3: barrier ----
    __syncthreads();

    // ---- phase 4: evaluate TB rows ----
#pragma unroll
    for (int r = 0; r < TB; ++r) {
        const float* xb = xs + r * DIN_;
        // all 6 gathers independent, issued together
        float gx[GPT][3];
#pragma unroll
        for (int gi = 0; gi < GPT; ++gi) {
            gx[gi][0] = xb[cc[gi][0]];
            gx[gi][1] = xb[cc[gi][1]];
            gx[gi][2] = xb[cc[gi][2]];
        }
        float o[GPT * 3];
#pragma unroll
        for (int gi = 0; gi < GPT; ++gi) {
            const float x0 = gx[gi][0], x1 = gx[gi][1], x2 = gx[gi][2];
            const float p01 = x0 * x1, p02 = x0 * x2, p12 = x1 * x2;
#pragma unroll
            for (int m = 0; m < 3; ++m) {
                o[gi * 3 + m] = CF[gi][m][0]
                              + CF[gi][m][1]*x0 + CF[gi][m][2]*x1 + CF[gi][m][3]*x2
                              + CF[gi][m][4]*p01 + CF[gi][m][5]*p02 + CF[gi][m][6]*p12;
            }
        }
        // 24 B contiguous per lane -> wave writes 1536 B contiguous
        float2* op = (float2*)(out + (size_t)(row0 + r) * (3 * G_) + (size_t)t * (3 * GPT));
        op[0] = make_float2(o[0], o[1]);
        op[1] = make_float2(o[2], o[3]);
        op[2] = make_float2(o[4], o[5]);
    }
}

extern "C" void kernel_launch(void* const* d_in, const int* in_sizes, int n_in,
                              void* d_out, int out_size, void* d_ws, size_t ws_size,
                              hipStream_t stream) {
    const float* x    = (const float*)d_in[0];
    const int*   conn = (const int*)d_in[1];
    const float* sel  = (const float*)d_in[2];
    const float* wg   = (const float*)d_in[3];
    float* out = (float*)d_out;

    hipLaunchKernelGGL(fredkin_fused_kernel, dim3(B_ / TB), dim3(TPB), 0, stream,
                       x, conn, sel, wg, out);
}